// Round 1
// 64.099 us; speedup vs baseline: 1.0133x; 1.0133x over previous
//
#include <hip/hip_runtime.h>

#define DEV __device__ __forceinline__
typedef float f32x2 __attribute__((ext_vector_type(2)));
typedef float f32x4 __attribute__((ext_vector_type(4)));

DEV float rdlane(float v, int l) {
  return __int_as_float(__builtin_amdgcn_readlane(__float_as_int(v), l));
}
DEV f32x2 pkfma(f32x2 a, f32x2 b, f32x2 c) { return __builtin_elementwise_fma(a, b, c); }
DEV f32x2 splat(float x) { return (f32x2){x, x}; }
DEV f32x2 swap2(f32x2 v) { return __builtin_shufflevector(v, v, 1, 0); }
DEV f32x2 cmul(f32x2 P, f32x2 F) {            // complex multiply P*F
  f32x2 t = swap2(P);
  f32x2 m = {-t.x, t.y};
  return pkfma(splat(F.y), m, splat(F.x) * P);
}

template <int CTRL>
DEV float dppmov(float v) {                   // pure-VALU lane move
  return __int_as_float(__builtin_amdgcn_update_dpp(
      0, __float_as_int(v), CTRL, 0xf, 0xf, true));
}
// xor-mask lane exchange. 1,2 = quad_perm DPP; 8 = row_ror:8 DPP;
// 4,16 = ds_swizzle immediate (no addr math, stays within 32-lane group).
template <int M>
DEV float xorl(float v) {
  if constexpr (M == 1)       return dppmov<0xB1>(v);
  else if constexpr (M == 2)  return dppmov<0x4E>(v);
  else if constexpr (M == 8)  return dppmov<0x128>(v);
  else if constexpr (M == 4)
    return __int_as_float(__builtin_amdgcn_ds_swizzle(__float_as_int(v), 0x101F));
  else /* M == 16 */
    return __int_as_float(__builtin_amdgcn_ds_swizzle(__float_as_int(v), 0x401F));
}

// Controlled rotation, target on LANE bit M. c1/s1 pre-masked by control
// (inactive lanes: c1=1, s1=0) unless control is an r-bit (R0/RS restrict r).
template <int M, bool CRX, int R0, int RS>
DEV void gate_lane(f32x2 amp[8], int lane, float c1, float s1) {
  const f32x2 C2 = splat(c1);
  if constexpr (CRX) {
    const f32x2 S2 = {s1, -s1};
#pragma unroll
    for (int r = R0; r < 8; r += RS) {
      f32x2 p;
      p.x = xorl<M>(amp[r].y);                // (p.im, p.re): swap folded in
      p.y = xorl<M>(amp[r].x);
      amp[r] = pkfma(S2, p, C2 * amp[r]);
    }
  } else {
    const float sp = (lane & M) ? s1 : -s1;
    const f32x2 SP = splat(sp);
#pragma unroll
    for (int r = R0; r < 8; r += RS) {
      f32x2 p;
      p.x = xorl<M>(amp[r].x);
      p.y = xorl<M>(amp[r].y);
      amp[r] = pkfma(SP, p, C2 * amp[r]);
    }
  }
}

// Controlled rotation, target on an r-bit: pair (I: tbit=0, J: tbit=1).
template <bool CRX>
DEV void gate_pair(f32x2& aI, f32x2& aJ, float c1, float s1) {
  const f32x2 C2 = splat(c1);
  f32x2 nI, nJ;
  if constexpr (CRX) {
    const f32x2 S2 = {s1, -s1};
    nI = pkfma(S2, swap2(aJ), C2 * aI);
    nJ = pkfma(S2, swap2(aI), C2 * aJ);
  } else {
    nI = pkfma(splat(-s1), aJ, C2 * aI);
    nJ = pkfma(splat(s1), aI, C2 * aJ);
  }
  aI = nI; aJ = nJ;
}

// One wave = TWO batch elements, one per 32-lane half (element = lane bit 5).
// Per lane: 8 complex amps (f32x2). Amp bits: lane bits 4..0 = qubits 0..4,
// r bits 2,1,0 = qubits 5,6,7.
// NOTE: min-waves-per-EU = 4 (VGPR cap 128, no spills). At the previous
// bound of 8 the 64-VGPR cap sat right at the hand-counted ~55-60 live
// peak and risked forced scratch spills; 4 waves/SIMD still covers the
// ~2k-cycle dependency depth (issue ~1.4k cyc/wave).
__global__ __launch_bounds__(256, 4) void qsim_kernel(const float* __restrict__ X,
                                                      const float* __restrict__ W,
                                                      float* __restrict__ out, int bs) {
  const int lane = threadIdx.x & 63;
  const int wave = blockIdx.x * (blockDim.x >> 6) + (threadIdx.x >> 6);
  const int b0 = wave * 2;
  if (b0 >= bs) return;

  // ---- entangling weight load (sincos deferred until after the chain) ----
  const float w = W[(((lane & 15) >> 3) << 4) + (lane & 7)];

  // ---- encoding chains: lane -> element (lane>>3)&1, qubit lane&7 (16 chains) ----
  const int ce = (lane >> 3) & 1;
  const int cq = lane & 7;
  int bb = b0 + ce; bb = bb >= bs ? bs - 1 : bb;
  const float* Xrow = X + (size_t)bb * 64;
  // This chain's 9 angles are contiguous at cq*9. Vector-load them as
  // dwordx4 + dwordx4 + dword (dword-aligned is fine on gfx950).
  // For cq==7 only ang[0] (=Xrow[63]) matters; shift the base to 55 so the
  // 9-float window [55..63] stays inside the row (no OOB on the last row).
  const int lb = (cq == 7) ? 55 : cq * 9;
  f32x4 v0, v1;
  __builtin_memcpy(&v0, Xrow + lb, 16);
  __builtin_memcpy(&v1, Xrow + lb + 4, 16);
  const float a8 = Xrow[lb + 8];
  float ang[9] = {v0.x, v0.y, v0.z, v0.w, v1.x, v1.y, v1.z, v1.w, a8};
  if (cq == 7) ang[0] = a8;               // q7 chain: single rotation on Xrow[63]

  const float Hc = 0.70710678118654752440f;
  f32x2 A = {Hc, 0.f}, B = {Hc, 0.f};     // column of (rotations * H)|0>
#pragma unroll
  for (int i = 0; i < 9; ++i) {
    float s, c;
    __sincosf(0.5f * ang[i], &s, &c);
    if (i > 0) {                          // qubit-7 chain: identity after i=0
      bool dead = (cq == 7);
      c = dead ? 1.f : c;
      s = dead ? 0.f : s;
    }
    if ((i & 1) == 0) {                   // RZ
      f32x2 nA = pkfma((f32x2){s, -s}, swap2(A), splat(c) * A);
      f32x2 nB = pkfma((f32x2){-s, s}, swap2(B), splat(c) * B);
      A = nA; B = nB;
    } else {                              // RY
      f32x2 nA = pkfma(splat(-s), B, splat(c) * A);
      f32x2 nB = pkfma(splat(c), B, splat(s) * A);
      A = nA; B = nB;
    }
  }

  // publish chain results: (A,B) per (element, qubit); 256 B per wave
  __shared__ f32x4 ldsAB[4][16];
  const int wvid = (threadIdx.x >> 6) & 3;
  if (lane < 16) ldsAB[wvid][lane] = (f32x4){A.x, A.y, B.x, B.y};
  __builtin_amdgcn_wave_barrier();        // same-wave DS ordering fence

  // ---- entangling weight sincos: lane g<16 holds gate g = l*8+i -> W[l*16+i] ----
  float sw, cw;
  __sincosf(0.5f * w, &sw, &cw);

  // ---- build product-state amplitudes (my half's element) ----
  const int half = lane >> 5;
  const int base = half * 8;
  const f32x2* b2 = (const f32x2*)&ldsAB[wvid][0];  // entry 2*k = A_k, 2*k+1 = B_k
  f32x2 P = b2[(base + 0) * 2 + ((lane >> 4) & 1)];
#pragma unroll
  for (int q = 1; q <= 4; ++q)
    P = cmul(P, b2[(base + q) * 2 + ((lane >> (4 - q)) & 1)]);
  f32x4 F5 = ldsAB[wvid][base + 5];
  f32x4 F6 = ldsAB[wvid][base + 6];
  f32x4 F7 = ldsAB[wvid][base + 7];
  f32x2 A5 = {F5.x, F5.y}, B5 = {F5.z, F5.w};
  f32x2 A6 = {F6.x, F6.y}, B6 = {F6.z, F6.w};
  f32x2 A7 = {F7.x, F7.y}, B7 = {F7.z, F7.w};
  f32x2 amp[8];
  {
    f32x2 t0 = cmul(P, A5), t1 = cmul(P, B5);
    f32x2 u00 = cmul(t0, A6), u01 = cmul(t0, B6);
    amp[0] = cmul(u00, A7); amp[1] = cmul(u00, B7);
    amp[2] = cmul(u01, A7); amp[3] = cmul(u01, B7);
    f32x2 u10 = cmul(t1, A6), u11 = cmul(t1, B6);
    amp[4] = cmul(u10, A7); amp[5] = cmul(u10, B7);
    amp[6] = cmul(u11, A7); amp[7] = cmul(u11, B7);
  }

  // ---- entangling: layer 0 = CRX, layer 1 = CRY; ctrl=q_i, tgt=q_{i+1} ----
#pragma unroll
  for (int l = 0; l < 2; ++l) {
    const bool isCRX = (l == 0);
#define CS(G, CBIT) \
    const float cg = rdlane(cw, G), sg = rdlane(sw, G); \
    const bool act = (lane >> (CBIT)) & 1; \
    const float c1 = act ? cg : 1.f, s1 = act ? sg : 0.f;
    { CS(l * 8 + 0, 4)                    // ctrl q0(b4) -> tgt q1(b3): DPP ror8
      if (isCRX) gate_lane<8, true, 0, 1>(amp, lane, c1, s1);
      else       gate_lane<8, false, 0, 1>(amp, lane, c1, s1); }
    { CS(l * 8 + 1, 3)                    // ctrl q1(b3) -> tgt q2(b2): swizzle xor4
      if (isCRX) gate_lane<4, true, 0, 1>(amp, lane, c1, s1);
      else       gate_lane<4, false, 0, 1>(amp, lane, c1, s1); }
    { CS(l * 8 + 2, 2)                    // ctrl q2(b2) -> tgt q3(b1): DPP quad
      if (isCRX) gate_lane<2, true, 0, 1>(amp, lane, c1, s1);
      else       gate_lane<2, false, 0, 1>(amp, lane, c1, s1); }
    { CS(l * 8 + 3, 1)                    // ctrl q3(b1) -> tgt q4(b0): DPP quad
      if (isCRX) gate_lane<1, true, 0, 1>(amp, lane, c1, s1);
      else       gate_lane<1, false, 0, 1>(amp, lane, c1, s1); }
    { CS(l * 8 + 4, 0)                    // ctrl q4(b0) -> tgt q5(r2): pairs (r,r+4)
#pragma unroll
      for (int r = 0; r < 4; ++r) {
        if (isCRX) gate_pair<true>(amp[r], amp[r + 4], c1, s1);
        else       gate_pair<false>(amp[r], amp[r + 4], c1, s1);
      } }
    {                                     // ctrl q5(r2) -> tgt q6(r1): r in {4..7}
      const float cg = rdlane(cw, l * 8 + 5), sg = rdlane(sw, l * 8 + 5);
      if (isCRX) { gate_pair<true>(amp[4], amp[6], cg, sg);
                   gate_pair<true>(amp[5], amp[7], cg, sg); }
      else       { gate_pair<false>(amp[4], amp[6], cg, sg);
                   gate_pair<false>(amp[5], amp[7], cg, sg); }
    }
    {                                     // ctrl q6(r1) -> tgt q7(r0): r in {2,3,6,7}
      const float cg = rdlane(cw, l * 8 + 6), sg = rdlane(sw, l * 8 + 6);
      if (isCRX) { gate_pair<true>(amp[2], amp[3], cg, sg);
                   gate_pair<true>(amp[6], amp[7], cg, sg); }
      else       { gate_pair<false>(amp[2], amp[3], cg, sg);
                   gate_pair<false>(amp[6], amp[7], cg, sg); }
    }
    {                                     // ctrl q7(r0) -> tgt q0(b4): odd r, swizzle xor16
      const float cg = rdlane(cw, l * 8 + 7), sg = rdlane(sw, l * 8 + 7);
      if (isCRX) gate_lane<16, true, 1, 2>(amp, lane, cg, sg);
      else       gate_lane<16, false, 1, 2>(amp, lane, cg, sg);
    }
#undef CS
  }

  // ---- measurement ----
  float p[8];
#pragma unroll
  for (int r = 0; r < 8; ++r) p[r] = fmaf(amp[r].x, amp[r].x, amp[r].y * amp[r].y);
  float s01 = p[0] + p[1], s23 = p[2] + p[3], s45 = p[4] + p[5], s67 = p[6] + p[7];
  float sL = s01 + s23, sH = s45 + s67;
  float wv = sL + sH;                     // WHT input -> qubits 0..4 (lane bits)
  f32x2 D = {sL - sH,                     // q5 (r bit2)
             (s01 + s45) - (s23 + s67)};  // q6 (r bit1)
  float d7 = (p[0] - p[1]) + (p[2] - p[3]) + (p[4] - p[5]) + (p[6] - p[7]); // q7

#define STAGE(K, M)                                   \
  {                                                   \
    float pp = xorl<M>(wv);                           \
    wv = pp + (((lane >> K) & 1) ? -wv : wv);         \
    f32x2 pd;                                         \
    pd.x = xorl<M>(D.x);                              \
    pd.y = xorl<M>(D.y);                              \
    D = D + pd;                                       \
    d7 += xorl<M>(d7);                                \
  }
  STAGE(0, 1) STAGE(1, 2) STAGE(2, 4) STAGE(3, 8) STAGE(4, 16)
#undef STAGE

  // ---- gather & store: each half writes its element's 8 outputs ----
  const int lpos = lane & 31;
  const int srcl = (lane & 32) + (16 >> lpos);   // q0..q4 sit in WHT lanes 16,8,4,2,1
  float g = __shfl(wv, srcl, 64);
  float val = (lpos == 5) ? D.x : (lpos == 6) ? D.y : (lpos == 7) ? d7 : g;
  const int brow = b0 + half;
  if (lpos < 8 && brow < bs) out[(size_t)brow * 8 + lpos] = val;
}

extern "C" void kernel_launch(void* const* d_in, const int* in_sizes, int n_in,
                              void* d_out, int out_size, void* d_ws, size_t ws_size,
                              hipStream_t stream) {
  const float* X = (const float*)d_in[0];   // (bs, 64) float32
  const float* W = (const float*)d_in[1];   // (2, 16) float32
  float* out = (float*)d_out;               // (bs, 8) float32
  int bs = in_sizes[0] / 64;
  int waves = (bs + 1) / 2;                 // 2 elements per wave
  const int waves_per_block = 4;
  const int threads = waves_per_block * 64;
  int blocks = (waves + waves_per_block - 1) / waves_per_block;
  hipLaunchKernelGGL(qsim_kernel, dim3(blocks), dim3(threads), 0, stream, X, W, out, bs);
}

// Round 2
// 62.315 us; speedup vs baseline: 1.0423x; 1.0286x over previous
//
#include <hip/hip_runtime.h>

#define DEV __device__ __forceinline__
typedef float f32x2 __attribute__((ext_vector_type(2)));
typedef float f32x4 __attribute__((ext_vector_type(4)));

DEV float rdlane(float v, int l) {
  return __int_as_float(__builtin_amdgcn_readlane(__float_as_int(v), l));
}
DEV f32x2 pkfma(f32x2 a, f32x2 b, f32x2 c) { return __builtin_elementwise_fma(a, b, c); }
DEV f32x2 splat(float x) { return (f32x2){x, x}; }
DEV f32x2 swap2(f32x2 v) { return __builtin_shufflevector(v, v, 1, 0); }
DEV f32x2 cmul(f32x2 P, f32x2 F) {            // complex multiply P*F
  f32x2 t = swap2(P);
  f32x2 m = {-t.x, t.y};
  return pkfma(splat(F.y), m, splat(F.x) * P);
}

template <int CTRL>
DEV float dppmov(float v) {                   // pure-VALU lane move
  return __int_as_float(__builtin_amdgcn_update_dpp(
      0, __float_as_int(v), CTRL, 0xf, 0xf, true));
}
// xor-mask lane exchange. 1,2 = quad_perm DPP; 8 = row_ror:8 DPP (xor within
// 16-lane row); 4 = ds_swizzle immediate. All stay within the 16-lane group.
template <int M>
DEV float xorl(float v) {
  if constexpr (M == 1)       return dppmov<0xB1>(v);
  else if constexpr (M == 2)  return dppmov<0x4E>(v);
  else if constexpr (M == 8)  return dppmov<0x128>(v);
  else /* M == 4 */
    return __int_as_float(__builtin_amdgcn_ds_swizzle(__float_as_int(v), 0x101F));
}

// Controlled rotation, target on LANE bit M (within the 16-lane group).
// c1/s1 pre-masked by control (inactive lanes: c1=1, s1=0) unless control is
// an r-bit (then R0/RS restrict which of the 16 register amps participate).
template <int M, bool CRX, int R0, int RS>
DEV void gate_lane16(f32x2 amp[16], int lane, float c1, float s1) {
  const f32x2 C2 = splat(c1);
  if constexpr (CRX) {
    const f32x2 S2 = {s1, -s1};
#pragma unroll
    for (int r = R0; r < 16; r += RS) {
      f32x2 p;
      p.x = xorl<M>(amp[r].y);                // (p.im, p.re): swap folded in
      p.y = xorl<M>(amp[r].x);
      amp[r] = pkfma(S2, p, C2 * amp[r]);
    }
  } else {
    const float sp = (lane & M) ? s1 : -s1;
    const f32x2 SP = splat(sp);
#pragma unroll
    for (int r = R0; r < 16; r += RS) {
      f32x2 p;
      p.x = xorl<M>(amp[r].x);
      p.y = xorl<M>(amp[r].y);
      amp[r] = pkfma(SP, p, C2 * amp[r]);
    }
  }
}

// Controlled rotation, target on an r-bit: pair (I: tbit=0, J: tbit=1).
template <bool CRX>
DEV void gate_pair(f32x2& aI, f32x2& aJ, float c1, float s1) {
  const f32x2 C2 = splat(c1);
  f32x2 nI, nJ;
  if constexpr (CRX) {
    const f32x2 S2 = {s1, -s1};
    nI = pkfma(S2, swap2(aJ), C2 * aI);
    nJ = pkfma(S2, swap2(aI), C2 * aJ);
  } else {
    nI = pkfma(splat(-s1), aJ, C2 * aI);
    nJ = pkfma(splat(s1), aI, C2 * aJ);
  }
  aI = nI; aJ = nJ;
}

// One wave = FOUR batch elements, one per 16-lane group (element = lane>>4).
// Per lane: 16 complex amps (f32x2). State-index map (q0 = MSB as in ref):
//   lane bits 3..0  = qubits 0..3  (state bits 7..4)
//   r    bits 3..0  = qubits 4..7  (state bits 3..0)
// vs the previous 2-elem/wave layout this gives per layer 4 lane-gates +
// 4 pair-gates (was 5+3), only ONE ds_swizzle gate (was 2 + an M=16 WHT
// stage), chain-phase cost amortized over 4 elements, and HALF the waves
// (4096 = 4/SIMD, fully resident in one pass at launch_bounds(256,4)).
__global__ __launch_bounds__(256, 4) void qsim_kernel(const float* __restrict__ X,
                                                      const float* __restrict__ W,
                                                      float* __restrict__ out, int bs) {
  const int lane = threadIdx.x & 63;
  const int wave = blockIdx.x * (blockDim.x >> 6) + (threadIdx.x >> 6);
  const int b0 = wave * 4;
  if (b0 >= bs) return;

  // ---- entangling weight load (sincos deferred until after the chain) ----
  const float w = W[(((lane & 15) >> 3) << 4) + (lane & 7)];

  // ---- encoding chains: 32 chains = 4 elements x 8 qubits; lanes 32..63 dup ----
  const int cidx = lane & 31;
  const int ce = cidx >> 3;                 // element 0..3
  const int cq = cidx & 7;                  // qubit 0..7
  int bb = b0 + ce; bb = bb >= bs ? bs - 1 : bb;
  const float* Xrow = X + (size_t)bb * 64;
  // Chain's 9 angles are contiguous at cq*9 (dwordx4+dwordx4+dword). For
  // cq==7 only ang[0] (=Xrow[63]) matters; shift base to 55 to stay in-row.
  const int lb = (cq == 7) ? 55 : cq * 9;
  f32x4 v0, v1;
  __builtin_memcpy(&v0, Xrow + lb, 16);
  __builtin_memcpy(&v1, Xrow + lb + 4, 16);
  const float a8 = Xrow[lb + 8];
  float ang[9] = {v0.x, v0.y, v0.z, v0.w, v1.x, v1.y, v1.z, v1.w, a8};
  if (cq == 7) ang[0] = a8;                 // q7 chain: single rotation on Xrow[63]

  const float Hc = 0.70710678118654752440f;
  f32x2 A = {Hc, 0.f}, B = {Hc, 0.f};       // column of (rotations * H)|0>
#pragma unroll
  for (int i = 0; i < 9; ++i) {
    float s, c;
    __sincosf(0.5f * ang[i], &s, &c);
    if (i > 0) {                            // qubit-7 chain: identity after i=0
      bool dead = (cq == 7);
      c = dead ? 1.f : c;
      s = dead ? 0.f : s;
    }
    if ((i & 1) == 0) {                     // RZ
      f32x2 nA = pkfma((f32x2){s, -s}, swap2(A), splat(c) * A);
      f32x2 nB = pkfma((f32x2){-s, s}, swap2(B), splat(c) * B);
      A = nA; B = nB;
    } else {                                // RY
      f32x2 nA = pkfma(splat(-s), B, splat(c) * A);
      f32x2 nB = pkfma(splat(c), B, splat(s) * A);
      A = nA; B = nB;
    }
  }

  // publish chain results: (A,B) per chain = element*8+qubit; 512 B per wave
  __shared__ f32x4 ldsAB[4][32];
  const int wvid = (threadIdx.x >> 6) & 3;
  if (lane < 32) ldsAB[wvid][cidx] = (f32x4){A.x, A.y, B.x, B.y};
  __builtin_amdgcn_wave_barrier();          // same-wave DS ordering fence

  // ---- entangling weight sincos: lane g<16 holds gate g=l*8+i -> W[l*16+i] ----
  float sw, cw;
  __sincosf(0.5f * w, &sw, &cw);

  // ---- build product-state amplitudes (my group's element) ----
  const int grp = lane >> 4;                // element within wave
  const int cbase = grp * 8;                // chain base for this element
  const f32x2* b2 = (const f32x2*)&ldsAB[wvid][0];  // entry 2*c = A_c, 2*c+1 = B_c
  // P = product over q0..q3, selected by lane bits 3..0
  f32x2 P = b2[(cbase + 0) * 2 + ((lane >> 3) & 1)];
#pragma unroll
  for (int q = 1; q <= 3; ++q)
    P = cmul(P, b2[(cbase + q) * 2 + ((lane >> (3 - q)) & 1)]);
  f32x4 F4 = ldsAB[wvid][cbase + 4];
  f32x4 F5 = ldsAB[wvid][cbase + 5];
  f32x4 F6 = ldsAB[wvid][cbase + 6];
  f32x4 F7 = ldsAB[wvid][cbase + 7];
  f32x2 A4 = {F4.x, F4.y}, B4 = {F4.z, F4.w};
  f32x2 A5 = {F5.x, F5.y}, B5 = {F5.z, F5.w};
  f32x2 A6 = {F6.x, F6.y}, B6 = {F6.z, F6.w};
  f32x2 A7 = {F7.x, F7.y}, B7 = {F7.z, F7.w};
  // amp[r], r bits (3,2,1,0) = (q4,q5,q6,q7) choice; t0/t1 branch = q4=0/1
  f32x2 amp[16];
  {
    f32x2 t0 = cmul(P, A4);
    f32x2 u00 = cmul(t0, A5), u01 = cmul(t0, B5);
    f32x2 v;
    v = cmul(u00, A6); amp[0] = cmul(v, A7);  amp[1] = cmul(v, B7);
    v = cmul(u00, B6); amp[2] = cmul(v, A7);  amp[3] = cmul(v, B7);
    v = cmul(u01, A6); amp[4] = cmul(v, A7);  amp[5] = cmul(v, B7);
    v = cmul(u01, B6); amp[6] = cmul(v, A7);  amp[7] = cmul(v, B7);
    f32x2 t1 = cmul(P, B4);
    f32x2 u10 = cmul(t1, A5), u11 = cmul(t1, B5);
    v = cmul(u10, A6); amp[8] = cmul(v, A7);  amp[9] = cmul(v, B7);
    v = cmul(u10, B6); amp[10] = cmul(v, A7); amp[11] = cmul(v, B7);
    v = cmul(u11, A6); amp[12] = cmul(v, A7); amp[13] = cmul(v, B7);
    v = cmul(u11, B6); amp[14] = cmul(v, A7); amp[15] = cmul(v, B7);
  }

  // ---- entangling: layer 0 = CRX, layer 1 = CRY; ctrl=q_i, tgt=q_{i+1} ----
#pragma unroll
  for (int l = 0; l < 2; ++l) {
    const bool isCRX = (l == 0);
#define CS(G, CBIT) \
    const float cg = rdlane(cw, G), sg = rdlane(sw, G); \
    const bool act = (lane >> (CBIT)) & 1; \
    const float c1 = act ? cg : 1.f, s1 = act ? sg : 0.f;
    { CS(l * 8 + 0, 3)                      // ctrl q0(b3) -> tgt q1(b2): swizzle xor4
      if (isCRX) gate_lane16<4, true, 0, 1>(amp, lane, c1, s1);
      else       gate_lane16<4, false, 0, 1>(amp, lane, c1, s1); }
    { CS(l * 8 + 1, 2)                      // ctrl q1(b2) -> tgt q2(b1): DPP quad
      if (isCRX) gate_lane16<2, true, 0, 1>(amp, lane, c1, s1);
      else       gate_lane16<2, false, 0, 1>(amp, lane, c1, s1); }
    { CS(l * 8 + 2, 1)                      // ctrl q2(b1) -> tgt q3(b0): DPP quad
      if (isCRX) gate_lane16<1, true, 0, 1>(amp, lane, c1, s1);
      else       gate_lane16<1, false, 0, 1>(amp, lane, c1, s1); }
    { CS(l * 8 + 3, 0)                      // ctrl q3(b0) -> tgt q4(r3): pairs (r,r+8)
#pragma unroll
      for (int r = 0; r < 8; ++r) {
        if (isCRX) gate_pair<true>(amp[r], amp[r + 8], c1, s1);
        else       gate_pair<false>(amp[r], amp[r + 8], c1, s1);
      } }
    {                                       // ctrl q4(r3) -> tgt q5(r2): r>=8 pairs
      const float cg = rdlane(cw, l * 8 + 4), sg = rdlane(sw, l * 8 + 4);
#pragma unroll
      for (int r = 8; r < 12; ++r) {
        if (isCRX) gate_pair<true>(amp[r], amp[r + 4], cg, sg);
        else       gate_pair<false>(amp[r], amp[r + 4], cg, sg);
      }
    }
    {                                       // ctrl q5(r2) -> tgt q6(r1): bit2=1 pairs
      const float cg = rdlane(cw, l * 8 + 5), sg = rdlane(sw, l * 8 + 5);
      if (isCRX) { gate_pair<true>(amp[4], amp[6], cg, sg);
                   gate_pair<true>(amp[5], amp[7], cg, sg);
                   gate_pair<true>(amp[12], amp[14], cg, sg);
                   gate_pair<true>(amp[13], amp[15], cg, sg); }
      else       { gate_pair<false>(amp[4], amp[6], cg, sg);
                   gate_pair<false>(amp[5], amp[7], cg, sg);
                   gate_pair<false>(amp[12], amp[14], cg, sg);
                   gate_pair<false>(amp[13], amp[15], cg, sg); }
    }
    {                                       // ctrl q6(r1) -> tgt q7(r0): bit1=1 pairs
      const float cg = rdlane(cw, l * 8 + 6), sg = rdlane(sw, l * 8 + 6);
      if (isCRX) { gate_pair<true>(amp[2], amp[3], cg, sg);
                   gate_pair<true>(amp[6], amp[7], cg, sg);
                   gate_pair<true>(amp[10], amp[11], cg, sg);
                   gate_pair<true>(amp[14], amp[15], cg, sg); }
      else       { gate_pair<false>(amp[2], amp[3], cg, sg);
                   gate_pair<false>(amp[6], amp[7], cg, sg);
                   gate_pair<false>(amp[10], amp[11], cg, sg);
                   gate_pair<false>(amp[14], amp[15], cg, sg); }
    }
    {                                       // ctrl q7(r0) -> tgt q0(b3): odd r, DPP ror8
      const float cg = rdlane(cw, l * 8 + 7), sg = rdlane(sw, l * 8 + 7);
      if (isCRX) gate_lane16<8, true, 1, 2>(amp, lane, cg, sg);
      else       gate_lane16<8, false, 1, 2>(amp, lane, cg, sg);
    }
#undef CS
  }

  // ---- measurement: per-lane signed partial sums over r bits ----
  float p[16];
#pragma unroll
  for (int r = 0; r < 16; ++r) p[r] = fmaf(amp[r].x, amp[r].x, amp[r].y * amp[r].y);
  float s2[8], d2[8];
#pragma unroll
  for (int k = 0; k < 8; ++k) { s2[k] = p[2 * k] + p[2 * k + 1]; d2[k] = p[2 * k] - p[2 * k + 1]; }
  float d7 = ((d2[0] + d2[1]) + (d2[2] + d2[3])) + ((d2[4] + d2[5]) + (d2[6] + d2[7]));
  float s4[4], e4[4];
#pragma unroll
  for (int k = 0; k < 4; ++k) { s4[k] = s2[2 * k] + s2[2 * k + 1]; e4[k] = s2[2 * k] - s2[2 * k + 1]; }
  float d6 = (e4[0] + e4[1]) + (e4[2] + e4[3]);
  float s8a = s4[0] + s4[1], s8b = s4[2] + s4[3];
  float d5 = (s4[0] - s4[1]) + (s4[2] - s4[3]);
  float S = s8a + s8b;                      // WHT input -> qubits 0..3 (lane bits)
  float d4 = s8a - s8b;
  f32x2 D45 = {d4, d5}, D67 = {d6, d7};     // plain group-sums for q4..q7

  // 4-stage signed WHT on S (qubit b read from group lane 2^b after stages),
  // plain reduction on D packs. All exchanges within the 16-lane group.
#define STG(K, M)                                     \
  {                                                   \
    float pp = xorl<M>(S);                            \
    S = pp + (((lane >> K) & 1) ? -S : S);            \
    f32x2 qa, qb;                                     \
    qa.x = xorl<M>(D45.x); qa.y = xorl<M>(D45.y);     \
    D45 = D45 + qa;                                   \
    qb.x = xorl<M>(D67.x); qb.y = xorl<M>(D67.y);     \
    D67 = D67 + qb;                                   \
  }
  STG(0, 1) STG(1, 2) STG(2, 4) STG(3, 8)
#undef STG

  // ---- gather & store: lanes k<8 of each group write element's 8 outputs ----
  const int lpos = lane & 15;
  const int srcl = (lane & 48) + (8 >> lpos);    // q0..q3 sit in WHT lanes 8,4,2,1
  float g = __shfl(S, srcl, 64);
  float val = (lpos == 4) ? D45.x : (lpos == 5) ? D45.y
            : (lpos == 6) ? D67.x : (lpos == 7) ? D67.y : g;
  const int brow = b0 + (lane >> 4);
  if (lpos < 8 && brow < bs) out[(size_t)brow * 8 + lpos] = val;
}

extern "C" void kernel_launch(void* const* d_in, const int* in_sizes, int n_in,
                              void* d_out, int out_size, void* d_ws, size_t ws_size,
                              hipStream_t stream) {
  const float* X = (const float*)d_in[0];   // (bs, 64) float32
  const float* W = (const float*)d_in[1];   // (2, 16) float32
  float* out = (float*)d_out;               // (bs, 8) float32
  int bs = in_sizes[0] / 64;
  int waves = (bs + 3) / 4;                 // 4 elements per wave
  const int waves_per_block = 4;
  const int threads = waves_per_block * 64;
  int blocks = (waves + waves_per_block - 1) / waves_per_block;
  hipLaunchKernelGGL(qsim_kernel, dim3(blocks), dim3(threads), 0, stream, X, W, out, bs);
}